// Round 2
// baseline (2372.041 us; speedup 1.0000x reference)
//
#include <hip/hip_runtime.h>
#include <math.h>

#define NPTS 16384
#define NCTR 1024
#define BATCH 8
#define NCELL 512  // 8x8x8 Morton cells

typedef unsigned long long u64;
typedef unsigned int u32;

// Bit-exact squared distance matching numpy: ((dx*dx + dy*dy) + dz*dz),
// each op individually IEEE-rounded (no FMA contraction).
__device__ __forceinline__ float sq_dist(float x, float y, float z,
                                         float cx, float cy, float cz) {
  float dx = __fsub_rn(x, cx);
  float dy = __fsub_rn(y, cy);
  float dz = __fsub_rn(z, cz);
  return __fadd_rn(__fadd_rn(__fmul_rn(dx, dx), __fmul_rn(dy, dy)), __fmul_rn(dz, dz));
}

__device__ __forceinline__ float silu_f(float x) {
  return x / (1.0f + __expf(-x));
}

__device__ __forceinline__ u64 kmax(u64 a, u64 b) { return a > b ? a : b; }

__device__ __forceinline__ int morton_cell(float x, float y, float z) {
  int mx = min(7, max(0, (int)(x * 8.0f)));
  int my = min(7, max(0, (int)(y * 8.0f)));
  int mz = min(7, max(0, (int)(z * 8.0f)));
  int m = 0;
#pragma unroll
  for (int k = 0; k < 3; ++k) {
    m |= ((mx >> k) & 1) << (3 * k + 2);
    m |= ((my >> k) & 1) << (3 * k + 1);
    m |= ((mz >> k) & 1) << (3 * k + 0);
  }
  return m;
}

// ---------------------------------------------------------------------------
// Kernel 0: DETERMINISTIC Morton counting sort, one block per batch.
// ---------------------------------------------------------------------------
__global__ __launch_bounds__(1024) void sort_kernel(
    const float* __restrict__ xyz, float* __restrict__ sxg,
    float* __restrict__ syg, float* __restrict__ szg, int* __restrict__ sog) {
  const int b = blockIdx.x, t = threadIdx.x;
  const float* X = xyz + (size_t)b * 3 * NPTS;
  const float* Y = X + NPTS;
  const float* Z = X + 2 * NPTS;
  __shared__ int cnt[NCELL];
  __shared__ int off[NCELL];
  __shared__ int start[NCELL];
  __shared__ int so_l[NPTS];  // 64 KB
  for (int e = t; e < NCELL; e += 1024) cnt[e] = 0;
  __syncthreads();
#pragma unroll
  for (int j = 0; j < 16; ++j) {
    const int n = t + (j << 10);
    atomicAdd(&cnt[morton_cell(X[n], Y[n], Z[n])], 1);
  }
  __syncthreads();
  if (t < NCELL) off[t] = cnt[t];
  __syncthreads();
  for (int d = 1; d < NCELL; d <<= 1) {  // Hillis-Steele inclusive scan
    int v = 0;
    if (t < NCELL) { v = off[t]; if (t >= d) v += off[t - d]; }
    __syncthreads();
    if (t < NCELL) off[t] = v;
    __syncthreads();
  }
  if (t < NCELL) { off[t] -= cnt[t]; start[t] = off[t]; }
  __syncthreads();
  // phase A: racy scatter of orig index (intra-cell order arbitrary)
#pragma unroll
  for (int j = 0; j < 16; ++j) {
    const int n = t + (j << 10);
    const int pos = atomicAdd(&off[morton_cell(X[n], Y[n], Z[n])], 1);
    so_l[pos] = n;
  }
  __syncthreads();
  // phase B: deterministic intra-cell order (ascending orig index)
  if (t < NCELL) {
    const int s0 = start[t], k = cnt[t];
    for (int i2 = 1; i2 < k; ++i2) {
      const int key = so_l[s0 + i2];
      int j2 = i2 - 1;
      while (j2 >= 0 && so_l[s0 + j2] > key) {
        so_l[s0 + j2 + 1] = so_l[s0 + j2];
        --j2;
      }
      so_l[s0 + j2 + 1] = key;
    }
  }
  __syncthreads();
  // phase C: deterministic rebuild
  float* sx = sxg + (size_t)b * NPTS;
  float* sy = syg + (size_t)b * NPTS;
  float* sz = szg + (size_t)b * NPTS;
  int* so = sog + (size_t)b * NPTS;
#pragma unroll
  for (int j = 0; j < 16; ++j) {
    const int pos = t + (j << 10);
    const int n = so_l[pos];
    so[pos] = n;
    sx[pos] = X[n];
    sy[pos] = Y[n];
    sz[pos] = Z[n];
  }
}

// ---------------------------------------------------------------------------
// Kernel 1: bbox-pruned FPS with HIERARCHICAL (per-64-pt-channel) pruning.
//  - per-channel packed min-key K = (dist_bits<<32)|((16383-n)<<14)|p kept in
//    registers; u64 min with constant low bits == fmin on dist, ties resolve
//    exactly as jnp.argmax (dist desc, orig-n asc).
//  - per-channel bboxes held lane-indexed: lane c (c<16) owns channel c's
//    bbox. One 19-op test pass evaluates all 16 channels in parallel;
//    __ballot -> wave-uniform SGPR mask; update bodies guarded by SCALAR
//    branches (skipped channel costs ~2 SALU, zero VALU).
//  - skip is bit-exact no-op elision: same monotone-rounding + 0.9999-margin
//    argument as the previous wave-level test, with tighter (channel) boxes;
//    gv = wave max >= channel max, so the bound is conservative.
//  - mask==0 -> whole wave keeps cached gkey (subsumes old wave-level skip;
//    strictly more frequent since channel boxes are subsets of the wave box).
//  - fps indices buffered in LDS (no vmem in the loop -> barrier drains only
//    lgkm); block reduce is an explicit depth-4 tree.
// ---------------------------------------------------------------------------
#define CH_LIST(F) \
  F(0,a0)  F(1,a1)  F(2,a2)  F(3,a3)  F(4,a0)  F(5,a1)  F(6,a2)  F(7,a3)  \
  F(8,a0)  F(9,a1)  F(10,a2) F(11,a3) F(12,a0) F(13,a1) F(14,a2) F(15,a3)

__global__ __launch_bounds__(1024)
void fps_kernel(const float* __restrict__ xyz, const float* __restrict__ sxg,
                const float* __restrict__ syg, const float* __restrict__ szg,
                const int* __restrict__ sog, int* __restrict__ fps_idx) {
  const int b = blockIdx.x;
  const int t = threadIdx.x;
  const int w = t >> 6, lane = t & 63;
  const float* X = xyz + (size_t)b * 3 * NPTS;
  const float* Y = X + NPTS;
  const float* Z = X + 2 * NPTS;
  const float* SX = sxg + (size_t)b * NPTS;
  const float* SY = syg + (size_t)b * NPTS;
  const float* SZ = szg + (size_t)b * NPTS;
  const int* SO = sog + (size_t)b * NPTS;

  __shared__ float sxy[2 * NPTS];  // 128 KB interleaved sorted x,y
  __shared__ u64 s_key[32];        // [parity][16 waves]
  __shared__ int fps_lds[NCTR];    // buffered output indices (4 KB)

#define DECL_CH(c, acc) float z##c; u64 K##c;
  CH_LIST(DECL_CH)
#undef DECL_CH

  const int pbase = (w << 10) + lane;

  // lane-indexed channel bboxes: lane c (c<16) holds channel c's bbox.
  float bmnx = __builtin_inff(), bmxx = -__builtin_inff();
  float bmny = __builtin_inff(), bmxy = -__builtin_inff();
  float bmnz = __builtin_inff(), bmxz = -__builtin_inff();

#define INIT_CH(c, acc)                                         \
  {                                                             \
    const int p = pbase + (c << 6);                             \
    const float xv = SX[p], yv = SY[p], zv = SZ[p];             \
    sxy[2 * p] = xv; sxy[2 * p + 1] = yv;                       \
    z##c = zv;                                                  \
    const int o = SO[p];                                        \
    K##c = ((u64)0x7F800000u << 32) |                           \
           (u64)(((u32)(16383 - o) << 14) | (u32)p);            \
    float mnx = xv, mxx = xv, mny = yv, mxy = yv;               \
    float mnz = zv, mxz = zv;                                   \
    _Pragma("unroll")                                           \
    for (int off = 32; off >= 1; off >>= 1) {                   \
      mnx = fminf(mnx, __shfl_xor(mnx, off));                   \
      mxx = fmaxf(mxx, __shfl_xor(mxx, off));                   \
      mny = fminf(mny, __shfl_xor(mny, off));                   \
      mxy = fmaxf(mxy, __shfl_xor(mxy, off));                   \
      mnz = fminf(mnz, __shfl_xor(mnz, off));                   \
      mxz = fmaxf(mxz, __shfl_xor(mxz, off));                   \
    }                                                           \
    if (lane == c) {                                            \
      bmnx = mnx; bmxx = mxx; bmny = mny;                       \
      bmxy = mxy; bmnz = mnz; bmxz = mxz;                       \
    }                                                           \
  }
  CH_LIST(INIT_CH)
#undef INIT_CH

#define PIN_CH(c, acc) asm volatile("" : "+v"(z##c));
  CH_LIST(PIN_CH)
#undef PIN_CH

  if (t == 0) fps_lds[0] = 0;
  __syncthreads();  // LDS staging complete

  // first centroid = original point 0 (uniform loads)
  float cx = X[0], cy = Y[0], cz = Z[0];
  u64 gkey = ((u64)0x7F800000u << 32);  // gv=+inf => forces update at i=1

  for (int i = 1; i < NCTR; ++i) {
    // per-channel conservative skip tests, evaluated in parallel by lanes
    // 0..15 (lanes >=16 have inf-boxes -> lb=+inf -> always "skip").
    const float gv = __uint_as_float((u32)(gkey >> 32));
    const float ux = fmaxf(fmaxf(__fsub_rn(bmnx, cx), __fsub_rn(cx, bmxx)), 0.0f);
    const float uy = fmaxf(fmaxf(__fsub_rn(bmny, cy), __fsub_rn(cy, bmxy)), 0.0f);
    const float uz = fmaxf(fmaxf(__fsub_rn(bmnz, cz), __fsub_rn(cz, bmxz)), 0.0f);
    const float lb = __fadd_rn(__fadd_rn(__fmul_rn(ux, ux), __fmul_rn(uy, uy)),
                               __fmul_rn(uz, uz));
    const u64 mask = __ballot(!(__fmul_rn(lb, 0.9999f) >= gv));
    if (mask != 0ull) {
      // unconditional LDS reads (DS pipe, no VALU): latency overlaps rebuild
#define READ_CH(c, acc) \
      const float2 xy##c = *(const float2*)(sxy + 2 * (pbase + (c << 6)));
      CH_LIST(READ_CH)
#undef READ_CH
      // scalar-guarded updates: only channels whose bbox is within reach
#define UPD_CH(c, acc)                                                   \
      if (mask & (1ull << c)) {                                          \
        const float dd = sq_dist(xy##c.x, xy##c.y, z##c, cx, cy, cz);    \
        const u64 cand =                                                 \
            ((u64)__float_as_uint(dd) << 32) | (u64)(u32)K##c;           \
        K##c = cand < K##c ? cand : K##c;                                \
      }
      CH_LIST(UPD_CH)
#undef UPD_CH
      // rebuild per-lane max over all 16 cached channel keys (dep-depth 4)
      u64 a0 = 0, a1 = 0, a2 = 0, a3 = 0;
#define MAX_CH(c, acc) acc = kmax(acc, K##c);
      CH_LIST(MAX_CH)
#undef MAX_CH
      u64 k = kmax(kmax(a0, a1), kmax(a2, a3));
      // wave argmax butterfly over u64 keys
#pragma unroll
      for (int off = 32; off >= 1; off >>= 1)
        k = kmax(k, __shfl_xor(k, off));
      gkey = k;
    }
    const int base = (i & 1) << 4;
    if (lane == 0) s_key[base + w] = gkey;
    __syncthreads();  // the ONLY barrier per step (lgkm only: no vmem in loop)

    // block reduce: explicit depth-4 tree over 16 broadcast b64 reads
    const u64 k0 = s_key[base + 0], k1 = s_key[base + 1];
    const u64 k2 = s_key[base + 2], k3 = s_key[base + 3];
    const u64 k4 = s_key[base + 4], k5 = s_key[base + 5];
    const u64 k6 = s_key[base + 6], k7 = s_key[base + 7];
    const u64 k8 = s_key[base + 8], k9 = s_key[base + 9];
    const u64 k10 = s_key[base + 10], k11 = s_key[base + 11];
    const u64 k12 = s_key[base + 12], k13 = s_key[base + 13];
    const u64 k14 = s_key[base + 14], k15 = s_key[base + 15];
    const u64 m01 = kmax(k0, k1), m23 = kmax(k2, k3);
    const u64 m45 = kmax(k4, k5), m67 = kmax(k6, k7);
    const u64 m89 = kmax(k8, k9), mab = kmax(k10, k11);
    const u64 mcd = kmax(k12, k13), mef = kmax(k14, k15);
    const u64 m01m = kmax(m01, m23), m45m = kmax(m45, m67);
    const u64 m89m = kmax(m89, mab), mcdm = kmax(mcd, mef);
    const u64 m = kmax(kmax(m01m, m45m), kmax(m89m, mcdm));

    const u32 lowb = (u32)m;
    const int pw = (int)(lowb & 0x3FFFu);  // winner's sorted position
    if (t == 0) fps_lds[i] = 16383 - (int)((lowb >> 14) & 0x3FFFu);

    const int pu = __builtin_amdgcn_readfirstlane(pw);
    const float2 cxy = *(const float2*)(sxy + 2 * pu);  // one ds_read_b64
    cx = cxy.x;
    cy = cxy.y;
    cz = SZ[pu];  // one uniform (scalar) load, L2-warm sorted z
  }

  __syncthreads();
  // bulk writeout of buffered indices
  for (int e = t; e < NCTR; e += 1024) fps_idx[b * NCTR + e] = fps_lds[e];
}

// ---------------------------------------------------------------------------
// Kernel 2: ball query. One wave per centroid; scan points in ascending index
// order, collect first 32 with dist <= r^2, pad with first hit.
// ---------------------------------------------------------------------------
__global__ __launch_bounds__(256) void ballq_kernel(const float* __restrict__ xyz,
                                                    const int* __restrict__ fps_idx,
                                                    int* __restrict__ ball_idx) {
  const int gw = (blockIdx.x * 256 + threadIdx.x) >> 6;  // 0..8191
  const int lane = threadIdx.x & 63;
  const int b = gw >> 10;
  const float* X = xyz + (size_t)b * 3 * NPTS;
  const float* Y = X + NPTS;
  const float* Z = X + 2 * NPTS;
  const int c = fps_idx[gw];
  const float cx = X[c], cy = Y[c], cz = Z[c];
  int* out = ball_idx + (size_t)gw * 32;
  const float R2 = 0.04f;

  int cnt = 0, first = -1;
  for (int base = 0; base < NPTS; base += 64) {
    const int j = base + lane;
    const float d = sq_dist(X[j], Y[j], Z[j], cx, cy, cz);
    const bool inb = !(d > R2);
    const unsigned long long m = __ballot(inb);
    if (first < 0 && m != 0ull) first = base + __ffsll(m) - 1;
    if (inb) {
      const int pos = cnt + __popcll(m & ((1ull << lane) - 1ull));
      if (pos < 32) out[pos] = j;
    }
    cnt += __popcll(m);
    if (cnt >= 32) break;
  }
  for (int k = cnt + lane; k < 32; k += 64) out[k] = first;
}

// ---------------------------------------------------------------------------
// Kernel 2b: one-off weight transpose into workspace: wt[c][o] layouts.
// ---------------------------------------------------------------------------
__global__ __launch_bounds__(256) void transpose_w_kernel(
    const float* __restrict__ w0, const float* __restrict__ w1,
    const float* __restrict__ w2, float* __restrict__ wt0,
    float* __restrict__ wt1, float* __restrict__ wt2) {
  const int t0 = blockIdx.x * 256 + threadIdx.x;
  const int stride = gridDim.x * 256;
  for (int e = t0; e < 64 * 67; e += stride) {
    int o = e / 67, c = e - o * 67;
    wt0[c * 64 + o] = w0[e];
  }
  for (int e = t0; e < 128 * 64; e += stride) {
    int o = e >> 6, c = e & 63;
    wt1[c * 128 + o] = w1[e];
  }
  for (int e = t0; e < 256 * 128; e += stride) {
    int o = e >> 7, c = e & 127;
    wt2[c * 256 + o] = w2[e];
  }
}

// ---------------------------------------------------------------------------
// Kernel 3: fused gather + 3-layer pointwise MLP + mean over 32 samples.
// ---------------------------------------------------------------------------
__global__ __launch_bounds__(256, 2) void mlp_kernel(
    const float* __restrict__ xyz, const float* __restrict__ points,
    const int* __restrict__ fps_idx, const int* __restrict__ ball_idx,
    const float* __restrict__ wt0, const float* __restrict__ b0,
    const float* __restrict__ wt1, const float* __restrict__ b1,
    const float* __restrict__ wt2, const float* __restrict__ b2,
    float* __restrict__ out) {
  const int s = blockIdx.x, b = blockIdx.y, t = threadIdx.x;

  __shared__ float A1[64 * 36];    // layer0 out [o][k]
  __shared__ float A2[128 * 36];   // layer1 out [o][k]
  __shared__ float S[8704];        // scratch: A0+Wt0 | Wt1 | Wt2 chunk
  __shared__ float bias_sh[256];
  __shared__ int jidx[32];
  __shared__ float ctr[3];

  const int g = b * NCTR + s;

  // phase 1: indices, centroid, Wt0 [67][68] (stride-1 writes), bias0
  if (t < 32) jidx[t] = ball_idx[(size_t)g * 32 + t];
  if (t < 3) ctr[t] = xyz[((size_t)b * 3 + t) * NPTS + fps_idx[g]];
  float* A0 = S;              // [67][36]
  float* Wt0 = S + 67 * 36;   // [67][68]
  for (int e = t; e < 67 * 64; e += 256) {
    int c = e >> 6, o = e & 63;
    Wt0[c * 68 + o] = wt0[e];  // global coalesced, LDS stride-1
  }
  if (t < 64) bias_sh[t] = b0[t];
  __syncthreads();

  // phase 2: gather A0 = [xyz_norm(3); points(64)] x 32 samples
  for (int e = t; e < 67 * 32; e += 256) {
    int c = e >> 5, k = e & 31;
    int j = jidx[k];
    float v;
    if (c < 3)
      v = xyz[((size_t)b * 3 + c) * NPTS + j] - ctr[c];
    else
      v = points[((size_t)b * 64 + (c - 3)) * NPTS + j];
    A0[c * 36 + k] = v;
  }
  __syncthreads();

  // phase 3: layer 0 (67 -> 64), tile 4k x 2o
  {
    const int o0 = (t & 31) * 2;
    const int k0 = (t >> 5) * 4;
    float acc[4][2] = {{0.f, 0.f}, {0.f, 0.f}, {0.f, 0.f}, {0.f, 0.f}};
    for (int c = 0; c < 67; ++c) {
      const float4 a = *(const float4*)(A0 + c * 36 + k0);
      const float wv0 = Wt0[c * 68 + o0];
      const float wv1 = Wt0[c * 68 + o0 + 1];
      acc[0][0] = fmaf(a.x, wv0, acc[0][0]);
      acc[1][0] = fmaf(a.y, wv0, acc[1][0]);
      acc[2][0] = fmaf(a.z, wv0, acc[2][0]);
      acc[3][0] = fmaf(a.w, wv0, acc[3][0]);
      acc[0][1] = fmaf(a.x, wv1, acc[0][1]);
      acc[1][1] = fmaf(a.y, wv1, acc[1][1]);
      acc[2][1] = fmaf(a.z, wv1, acc[2][1]);
      acc[3][1] = fmaf(a.w, wv1, acc[3][1]);
    }
#pragma unroll
    for (int i = 0; i < 2; ++i) {
      const float bb = bias_sh[o0 + i];
      float4 r;
      r.x = silu_f(acc[0][i] + bb);
      r.y = silu_f(acc[1][i] + bb);
      r.z = silu_f(acc[2][i] + bb);
      r.w = silu_f(acc[3][i] + bb);
      *(float4*)(A1 + (o0 + i) * 36 + k0) = r;
    }
  }
  __syncthreads();

  // phase 4: stage Wt1 [64][132] (stride-1 writes), bias1
  float* Wt1 = S;
  for (int e = t; e < 128 * 64; e += 256) {
    int c = e >> 7, o = e & 127;
    Wt1[c * 132 + o] = wt1[e];
  }
  if (t < 128) bias_sh[t] = b1[t];
  __syncthreads();

  // phase 5: layer 1 (64 -> 128), tile 4k x 4o
  {
    const int o0 = (t & 31) * 4;
    const int k0 = (t >> 5) * 4;
    float acc[4][4];
#pragma unroll
    for (int kk = 0; kk < 4; ++kk)
#pragma unroll
      for (int oo = 0; oo < 4; ++oo) acc[kk][oo] = 0.f;
    for (int c = 0; c < 64; ++c) {
      const float4 a = *(const float4*)(A1 + c * 36 + k0);
      const float4 w = *(const float4*)(Wt1 + c * 132 + o0);
      const float av[4] = {a.x, a.y, a.z, a.w};
      const float wv[4] = {w.x, w.y, w.z, w.w};
#pragma unroll
      for (int kk = 0; kk < 4; ++kk)
#pragma unroll
        for (int oo = 0; oo < 4; ++oo)
          acc[kk][oo] = fmaf(av[kk], wv[oo], acc[kk][oo]);
    }
#pragma unroll
    for (int oo = 0; oo < 4; ++oo) {
      const float bb = bias_sh[o0 + oo];
      float4 r;
      r.x = silu_f(acc[0][oo] + bb);
      r.y = silu_f(acc[1][oo] + bb);
      r.z = silu_f(acc[2][oo] + bb);
      r.w = silu_f(acc[3][oo] + bb);
      *(float4*)(A2 + (o0 + oo) * 36 + k0) = r;
    }
  }
  __syncthreads();

  // phase 6: layer 2 (128 -> 256) in 4 chunks of 64 outputs + mean over k
  float* Wt2 = S;   // [128][68] per chunk
  float* P = A1;    // partial sums [64][9] (A1 dead)
  const int o0 = (t & 31) * 2;
  const int k0 = (t >> 5) * 4;
  const int kg = t >> 5;
  for (int chunk = 0; chunk < 4; ++chunk) {
    for (int e = t; e < 64 * 128; e += 256) {
      int c = e >> 6, o = e & 63;
      Wt2[c * 68 + o] = wt2[c * 256 + chunk * 64 + o];  // coalesced / stride-1
    }
    if (t < 64) bias_sh[t] = b2[chunk * 64 + t];
    __syncthreads();

    float acc[4][2] = {{0.f, 0.f}, {0.f, 0.f}, {0.f, 0.f}, {0.f, 0.f}};
    for (int c = 0; c < 128; ++c) {
      const float4 a = *(const float4*)(A2 + c * 36 + k0);
      const float wv0 = Wt2[c * 68 + o0];
      const float wv1 = Wt2[c * 68 + o0 + 1];
      acc[0][0] = fmaf(a.x, wv0, acc[0][0]);
      acc[1][0] = fmaf(a.y, wv0, acc[1][0]);
      acc[2][0] = fmaf(a.z, wv0, acc[2][0]);
      acc[3][0] = fmaf(a.w, wv0, acc[3][0]);
      acc[0][1] = fmaf(a.x, wv1, acc[0][1]);
      acc[1][1] = fmaf(a.y, wv1, acc[1][1]);
      acc[2][1] = fmaf(a.z, wv1, acc[2][1]);
      acc[3][1] = fmaf(a.w, wv1, acc[3][1]);
    }
#pragma unroll
    for (int i = 0; i < 2; ++i) {
      const float bb = bias_sh[o0 + i];
      float sum = silu_f(acc[0][i] + bb) + silu_f(acc[1][i] + bb) +
                  silu_f(acc[2][i] + bb) + silu_f(acc[3][i] + bb);
      P[(o0 + i) * 9 + kg] = sum;
    }
    __syncthreads();
    if (t < 64) {
      float tot = 0.f;
#pragma unroll
      for (int q = 0; q < 8; ++q) tot += P[t * 9 + q];
      out[((size_t)b * 256 + chunk * 64 + t) * NCTR + s] = tot * (1.0f / 32.0f);
    }
    __syncthreads();
  }
}

extern "C" void kernel_launch(void* const* d_in, const int* in_sizes, int n_in,
                              void* d_out, int out_size, void* d_ws, size_t ws_size,
                              hipStream_t stream) {
  const float* xyz = (const float*)d_in[0];
  const float* points = (const float*)d_in[1];
  const float* w0 = (const float*)d_in[2];
  const float* b0 = (const float*)d_in[3];
  const float* w1 = (const float*)d_in[4];
  const float* b1 = (const float*)d_in[5];
  const float* w2 = (const float*)d_in[6];
  const float* b2 = (const float*)d_in[7];
  float* out = (float*)d_out;

  int* fps = (int*)d_ws;                       // 8K ints
  int* bidx = (int*)d_ws + 8192;               // 256K ints
  float* wt0 = (float*)d_ws + 270336;          // 67*64
  float* wt1 = wt0 + 67 * 64;                  // 64*128
  float* wt2 = wt1 + 64 * 128;                 // 128*256
  float* sxg = (float*)d_ws + 315584;          // 8*16384 sorted x
  float* syg = sxg + BATCH * NPTS;             // sorted y
  float* szg = syg + BATCH * NPTS;             // sorted z
  int* sog = (int*)(szg + BATCH * NPTS);       // sorted orig idx (~3.4 MB total)

  transpose_w_kernel<<<64, 256, 0, stream>>>(w0, w1, w2, wt0, wt1, wt2);
  sort_kernel<<<BATCH, 1024, 0, stream>>>(xyz, sxg, syg, szg, sog);
  fps_kernel<<<BATCH, 1024, 0, stream>>>(xyz, sxg, syg, szg, sog, fps);
  ballq_kernel<<<2048, 256, 0, stream>>>(xyz, fps, bidx);
  mlp_kernel<<<dim3(NCTR, BATCH), 256, 0, stream>>>(xyz, points, fps, bidx,
                                                    wt0, b0, wt1, b1, wt2, b2, out);
}